// Round 1
// 420.792 us; speedup vs baseline: 1.2022x; 1.2022x over previous
//
#include <hip/hip_runtime.h>
#include <math.h>

typedef unsigned short u16;
typedef __attribute__((ext_vector_type(8))) short frag8;   // 8 bf16 = 4 VGPR
typedef __attribute__((ext_vector_type(4))) float f32x4;   // MFMA acc

__device__ __forceinline__ float eluf(float v) { return v > 0.f ? v : expm1f(v); }
__device__ __forceinline__ float geluf(float v) {
  return 0.5f * v * (1.f + erff(v * 0.70710678118654752f));
}
__device__ __forceinline__ u16 f2bf(float f) {
  union { float f; unsigned int i; } v; v.f = f;
  return (u16)((v.i + 0x7fffu + ((v.i >> 16) & 1u)) >> 16);
}

#define BN_S 0.99999500003749969f   /* 1/sqrt(1+1e-5) */

// ============================================================
// k_tws1: tws1[i][u] = s1[i] * tw_g[i%32][u-32+P_g]  (0 outside window)
//         c1[i]     = s1[i]*tb[i] + bn1_b[i]
// ============================================================
__global__ void k_tws1(const float* tw1, const float* tw2, const float* tw3, const float* tw4,
                       const float* tb1, const float* tb2, const float* tb3, const float* tb4,
                       const float* bn1g, const float* bn1b,
                       float* tws1, float* c1) {
  int idx = blockIdx.x * 256 + threadIdx.x;
  if (idx < 8320) {
    int i = idx / 65, u = idx - i * 65;
    int g = i >> 5, il = i & 31;
    const float* tws[4] = {tw1, tw2, tw3, tw4};
    const int P[4] = {7, 12, 25, 32};
    int c = u - 32;
    float s1 = bn1g[i] * BN_S;
    float val = 0.f;
    int p = P[g];
    if (c >= -p && c <= p) val = s1 * tws[g][il * (2 * p + 1) + (c + p)];
    tws1[idx] = val;
  } else if (idx < 8448) {
    int i = idx - 8320;
    int g = i >> 5, il = i & 31;
    const float* tbs[4] = {tb1, tb2, tb3, tb4};
    float s1 = bn1g[i] * BN_S;
    c1[i] = s1 * tbs[g][il] + bn1b[i];
  }
}

// ============================================================
// k_weff: one WAVE per (u, o). lane = kh.
// ============================================================
__global__ __launch_bounds__(256) void k_weff(const float* __restrict__ sw, const float* __restrict__ sb,
                                              const float* __restrict__ tws1, const float* __restrict__ c1,
                                              u16* __restrict__ Wb, float* __restrict__ biasEff) {
  const int lane = threadIdx.x & 63, wave = threadIdx.x >> 6;
  const int u = blockIdx.x;
  const int o = blockIdx.y * 4 + wave;
  const float* swp = sw + o * 8192 + lane;     // + i*64
  if (u < 65) {
    const float* tp = tws1 + u;                // + i*65 (wave-uniform)
    float a0 = 0.f, a1 = 0.f, a2 = 0.f, a3 = 0.f;
    #pragma unroll 8
    for (int i = 0; i < 128; i += 4) {
      a0 = fmaf(swp[(i + 0) * 64], tp[(i + 0) * 65], a0);
      a1 = fmaf(swp[(i + 1) * 64], tp[(i + 1) * 65], a1);
      a2 = fmaf(swp[(i + 2) * 64], tp[(i + 2) * 65], a2);
      a3 = fmaf(swp[(i + 3) * 64], tp[(i + 3) * 65], a3);
    }
    Wb[(u * 128 + o) * 64 + lane] = f2bf((a0 + a1) + (a2 + a3));
  } else {
    float pa = 0.f;
    #pragma unroll 8
    for (int i = 0; i < 128; i++)
      pa = fmaf(swp[i * 64], c1[i], pa);
    #pragma unroll
    for (int off = 32; off; off >>= 1) pa += __shfl_xor(pa, off);
    if (lane == 0) biasEff[o] = pa + sb[o];
  }
}

// ============================================================
// k_conv (MFMA): z[b][o][t] = elu(bn2(conv)).  (unchanged)
// ============================================================
__global__ __launch_bounds__(256) void k_conv(const float* __restrict__ x,
                                              const u16* __restrict__ Wb,
                                              const float* __restrict__ biasEff,
                                              const float* __restrict__ bn2g, const float* __restrict__ bn2b,
                                              float* __restrict__ z) {
  __shared__ u16 xs[128 * 88];   // 22.5 KB; row tt -> t0-32+tt, col kh
  const int tid = threadIdx.x;
  const int t0 = blockIdx.x * 64;
  const int o0 = blockIdx.y * 64;
  const int b  = blockIdx.z;

  #pragma unroll
  for (int i = 0; i < 8; i++) {
    int pos = tid + i * 256;
    int kh = pos >> 5;
    int tt = (pos & 31) * 4;
    int gt = t0 - 32 + tt;
    const float* xp = x + (b * 64 + kh) * 1000;
    float v[4];
    if (gt >= 0 && gt + 3 < 1000) {
      float4 f = *(const float4*)(xp + gt);
      v[0] = f.x; v[1] = f.y; v[2] = f.z; v[3] = f.w;
    } else {
      #pragma unroll
      for (int e = 0; e < 4; e++) { int g2 = gt + e; v[e] = (g2 >= 0 && g2 < 1000) ? xp[g2] : 0.f; }
    }
    #pragma unroll
    for (int e = 0; e < 4; e++) xs[(tt + e) * 88 + kh] = f2bf(v[e]);
  }
  __syncthreads();

  const int lane = tid & 63, wave = tid >> 6;
  const int wt = (wave & 1) * 32;
  const int wo = (wave >> 1) * 32;
  const int m = lane & 15, q = lane >> 4;

  f32x4 acc[2][2];
  #pragma unroll
  for (int i = 0; i < 2; i++)
    #pragma unroll
    for (int j = 0; j < 2; j++) acc[i][j] = (f32x4){0.f, 0.f, 0.f, 0.f};

  #pragma unroll 2
  for (int u = 0; u < 65; u++) {
    frag8 A[2][2], B[2][2];
    #pragma unroll
    for (int tp = 0; tp < 2; tp++)
      #pragma unroll
      for (int kc = 0; kc < 2; kc++)
        A[tp][kc] = *(const frag8*)&xs[(wt + tp * 16 + m + u) * 88 + kc * 32 + q * 8];
    #pragma unroll
    for (int op = 0; op < 2; op++)
      #pragma unroll
      for (int kc = 0; kc < 2; kc++)
        B[op][kc] = *(const frag8*)(Wb + ((u * 128) + o0 + wo + op * 16 + m) * 64 + kc * 32 + q * 8);
    #pragma unroll
    for (int tp = 0; tp < 2; tp++)
      #pragma unroll
      for (int op = 0; op < 2; op++) {
        acc[tp][op] = __builtin_amdgcn_mfma_f32_16x16x32_bf16(A[tp][0], B[op][0], acc[tp][op], 0, 0, 0);
        acc[tp][op] = __builtin_amdgcn_mfma_f32_16x16x32_bf16(A[tp][1], B[op][1], acc[tp][op], 0, 0, 0);
      }
  }

  #pragma unroll
  for (int op = 0; op < 2; op++) {
    int o = o0 + wo + op * 16 + m;
    float s2 = bn2g[o] * BN_S;
    float be = biasEff[o], b2 = bn2b[o];
    #pragma unroll
    for (int tp = 0; tp < 2; tp++) {
      #pragma unroll
      for (int r = 0; r < 4; r++) {
        int t = t0 + wt + tp * 16 + q * 4 + r;
        if (t < 1000)
          z[(b * 128 + o) * 1000 + t] = eluf((acc[tp][op][r] + be) * s2 + b2);
      }
    }
  }
}

// ============================================================
// k_pool: windows of 50, stride 15, npos=64. mean -> x1, log(var,ddof=1) -> x2.
// ============================================================
__global__ __launch_bounds__(128) void k_pool(const float* __restrict__ z, float* __restrict__ X) {
  int p = blockIdx.x, b = blockIdx.y, o = threadIdx.x;
  const float* zp = z + (b * 128 + o) * 1000 + p * 15;
  float s = 0.f, ss = 0.f;
  #pragma unroll
  for (int k = 0; k < 50; k++) { float v = zp[k]; s += v; ss = fmaf(v, v, ss); }
  float m = s * 0.02f;
  float var = (ss - s * m) * (1.f / 49.f);
  var = fminf(fmaxf(var, 1e-6f), 1e6f);
  X[(b * 64 + p) * 128 + o] = m;
  X[((16 + b) * 64 + p) * 128 + o] = logf(var);
}

// ============================================================
// k_cvt6: convert all encoder weights f32 -> bf16 into Wenc:
//   [ WQ(4*16384) | WK | WV | WO | F1W(4*65536) | F2W(4*65536) ]
// ============================================================
__global__ __launch_bounds__(256) void k_cvt6(const float* __restrict__ wq, const float* __restrict__ wk,
                                              const float* __restrict__ wv, const float* __restrict__ wo,
                                              const float* __restrict__ f1w, const float* __restrict__ f2w,
                                              u16* __restrict__ out) {
  int i = blockIdx.x * 256 + threadIdx.x;   // float4 index, total 196608
  if (i >= 196608) return;
  int fi = i * 4;
  const float* src; int off;
  if      (fi < 65536)  { src = wq;  off = fi; }
  else if (fi < 131072) { src = wk;  off = fi - 65536; }
  else if (fi < 196608) { src = wv;  off = fi - 131072; }
  else if (fi < 262144) { src = wo;  off = fi - 196608; }
  else if (fi < 524288) { src = f1w; off = fi - 262144; }
  else                  { src = f2w; off = fi - 524288; }
  float4 v = *(const float4*)(src + off);
  ushort4 p;
  p.x = f2bf(v.x); p.y = f2bf(v.y); p.z = f2bf(v.z); p.w = f2bf(v.w);
  *(ushort4*)(out + fi) = p;
}

// ============================================================
// k_enc: fused 4-layer transformer encoder. One block per sequence
// (32 sequences of 64 tokens x 128 dim), 512 threads (8 waves).
// X stays resident in LDS across all layers.
//   LDS: Xs f32[64][132] (33.8K) + Hs bf16[64][136] (17.4K)
//        + QKV f32[3][64][132] (101.4K, aliased by AOs/F1s bf16) = 152.6 KB
// ============================================================
__device__ __forceinline__ void ln128(const float* __restrict__ Xs, u16* __restrict__ Hs,
                                      const float* __restrict__ g, const float* __restrict__ b,
                                      int lane, int wave) {
  float g0 = g[lane], g1 = g[64 + lane], b0 = b[lane], b1 = b[64 + lane];
  #pragma unroll 1
  for (int rr = 0; rr < 8; rr++) {
    int r = wave * 8 + rr;
    float v0 = Xs[r * 132 + lane], v1 = Xs[r * 132 + 64 + lane];
    float s_ = v0 + v1;
    #pragma unroll
    for (int off = 32; off; off >>= 1) s_ += __shfl_xor(s_, off);
    float mn = s_ * (1.f / 128.f);
    float d0 = v0 - mn, d1 = v1 - mn;
    float qq = d0 * d0 + d1 * d1;
    #pragma unroll
    for (int off = 32; off; off >>= 1) qq += __shfl_xor(qq, off);
    float rs = rsqrtf(qq * (1.f / 128.f) + 1e-5f);
    Hs[r * 136 + lane]      = f2bf(d0 * rs * g0 + b0);
    Hs[r * 136 + 64 + lane] = f2bf(d1 * rs * g1 + b1);
  }
}

// 64xK=128 x 16-wide tile GEMM: acc[mt] over 4 m-tiles for this wave's n-strip.
// A: bf16 LDS [64][astride]; B: bf16 global, row n at Bsrc + m*bstride (+k).
__device__ __forceinline__ void gemm_tile(const u16* __restrict__ Asrc, int astride,
                                          const u16* __restrict__ Bsrc, int bstride,
                                          int m, int q, f32x4 acc[4]) {
  #pragma unroll
  for (int kc = 0; kc < 4; kc++) {
    frag8 Bf = *(const frag8*)(Bsrc + m * bstride + kc * 32 + q * 8);
    #pragma unroll
    for (int mt = 0; mt < 4; mt++) {
      frag8 Af = *(const frag8*)(Asrc + (mt * 16 + m) * astride + kc * 32 + q * 8);
      acc[mt] = __builtin_amdgcn_mfma_f32_16x16x32_bf16(Af, Bf, acc[mt], 0, 0, 0);
    }
  }
}

__global__ __launch_bounds__(512, 1) void k_enc(float* __restrict__ X,
                                                const u16* __restrict__ Wenc,
                                                const float* __restrict__ ln1g, const float* __restrict__ ln1b,
                                                const float* __restrict__ ln2g, const float* __restrict__ ln2b,
                                                const float* __restrict__ bq, const float* __restrict__ bk,
                                                const float* __restrict__ bv, const float* __restrict__ bo,
                                                const float* __restrict__ f1b, const float* __restrict__ f2b) {
  __shared__ float Xs[64 * 132];
  __shared__ u16   Hs[64 * 136];
  __shared__ float QKV[3 * 64 * 132];
  float* Qs = QKV;
  float* Ks = QKV + 64 * 132;
  float* Vs = QKV + 2 * 64 * 132;
  u16* AOs = (u16*)QKV;   // [64][136] bf16, aliases Qs (safe: Qs dead when written)
  u16* F1s = (u16*)QKV;   // [64][136] bf16, FF phase (QKV all dead)

  const int tid = threadIdx.x;
  const int lane = tid & 63, wave = tid >> 6;
  const int m = lane & 15, q = lane >> 4;
  float* Xg = X + blockIdx.x * 64 * 128;

  const u16* WQ  = Wenc;
  const u16* WK  = Wenc + 65536;
  const u16* WV  = Wenc + 131072;
  const u16* WO  = Wenc + 196608;
  const u16* F1W = Wenc + 262144;
  const u16* F2W = Wenc + 524288;

  for (int i = tid; i < 8192; i += 512) Xs[(i >> 7) * 132 + (i & 127)] = Xg[i];
  __syncthreads();

  #pragma unroll 1
  for (int l = 0; l < 4; l++) {
    const u16* wqb  = WQ  + l * 16384;
    const u16* wkb  = WK  + l * 16384;
    const u16* wvb  = WV  + l * 16384;
    const u16* wob  = WO  + l * 16384;
    const u16* f1wb = F1W + l * 65536;
    const u16* f2wb = F2W + l * 65536;
    const int n0 = wave * 16;

    // ---- LN1 -> Hs ----
    ln128(Xs, Hs, ln1g + l * 128, ln1b + l * 128, lane, wave);
    __syncthreads();

    // ---- QKV (each wave: one 16-wide n-strip of each of Q,K,V) ----
    {
      f32x4 aq[4], ak[4], av[4];
      #pragma unroll
      for (int mt = 0; mt < 4; mt++) { aq[mt] = (f32x4){0,0,0,0}; ak[mt] = (f32x4){0,0,0,0}; av[mt] = (f32x4){0,0,0,0}; }
      gemm_tile(Hs, 136, wqb + n0 * 128, 128, m, q, aq);
      gemm_tile(Hs, 136, wkb + n0 * 128, 128, m, q, ak);
      gemm_tile(Hs, 136, wvb + n0 * 128, 128, m, q, av);
      float bqv = bq[l * 128 + n0 + m];
      float bkv = bk[l * 128 + n0 + m];
      float bvv = bv[l * 128 + n0 + m];
      #pragma unroll
      for (int mt = 0; mt < 4; mt++)
        #pragma unroll
        for (int r = 0; r < 4; r++) {
          int row = mt * 16 + q * 4 + r;
          Qs[row * 132 + n0 + m] = aq[mt][r] + bqv;
          Ks[row * 132 + n0 + m] = ak[mt][r] + bkv;
          Vs[row * 132 + n0 + m] = av[mt][r] + bvv;
        }
    }
    __syncthreads();

    // ---- attention: wave = head, lane = query row; online softmax ----
    {
      const int h = wave, qr = lane;
      float qv[16];
      {
        const float4* qp = (const float4*)(Qs + qr * 132 + h * 16);
        #pragma unroll
        for (int j = 0; j < 4; j++) {
          float4 t = qp[j];
          qv[j * 4 + 0] = t.x; qv[j * 4 + 1] = t.y; qv[j * 4 + 2] = t.z; qv[j * 4 + 3] = t.w;
        }
      }
      __syncthreads();   // all Qs reads done before AOs (alias) writes
      const float* kbase = Ks + h * 16;
      const float* vbase = Vs + h * 16;
      float mrun = -1e30f, lrun = 0.f;
      float o[16];
      #pragma unroll
      for (int j = 0; j < 16; j++) o[j] = 0.f;
      #pragma unroll 1
      for (int k = 0; k < 64; k++) {
        const float4* kp = (const float4*)(kbase + k * 132);
        float4 k0 = kp[0], k1 = kp[1], k2 = kp[2], k3 = kp[3];
        float s0 = qv[0] * k0.x + qv[1] * k0.y + qv[2] * k0.z + qv[3] * k0.w;
        float s1 = qv[4] * k1.x + qv[5] * k1.y + qv[6] * k1.z + qv[7] * k1.w;
        float s2 = qv[8] * k2.x + qv[9] * k2.y + qv[10] * k2.z + qv[11] * k2.w;
        float s3 = qv[12] * k3.x + qv[13] * k3.y + qv[14] * k3.z + qv[15] * k3.w;
        float sc = ((s0 + s1) + (s2 + s3)) * 0.25f;
        float mn = fmaxf(mrun, sc);
        float corr = __expf(mrun - mn);
        float p = __expf(sc - mn);
        lrun = fmaf(lrun, corr, p);
        const float4* vp = (const float4*)(vbase + k * 132);
        float4 v0 = vp[0], v1 = vp[1], v2 = vp[2], v3 = vp[3];
        o[0]  = fmaf(o[0],  corr, p * v0.x); o[1]  = fmaf(o[1],  corr, p * v0.y);
        o[2]  = fmaf(o[2],  corr, p * v0.z); o[3]  = fmaf(o[3],  corr, p * v0.w);
        o[4]  = fmaf(o[4],  corr, p * v1.x); o[5]  = fmaf(o[5],  corr, p * v1.y);
        o[6]  = fmaf(o[6],  corr, p * v1.z); o[7]  = fmaf(o[7],  corr, p * v1.w);
        o[8]  = fmaf(o[8],  corr, p * v2.x); o[9]  = fmaf(o[9],  corr, p * v2.y);
        o[10] = fmaf(o[10], corr, p * v2.z); o[11] = fmaf(o[11], corr, p * v2.w);
        o[12] = fmaf(o[12], corr, p * v3.x); o[13] = fmaf(o[13], corr, p * v3.y);
        o[14] = fmaf(o[14], corr, p * v3.z); o[15] = fmaf(o[15], corr, p * v3.w);
        mrun = mn;
      }
      float inv = 1.f / lrun;
      u16* aop = AOs + qr * 136 + h * 16;
      #pragma unroll
      for (int j = 0; j < 16; j++) aop[j] = f2bf(o[j] * inv);
    }
    __syncthreads();

    // ---- O-proj + residual into Xs ----
    {
      f32x4 acc[4];
      #pragma unroll
      for (int mt = 0; mt < 4; mt++) acc[mt] = (f32x4){0,0,0,0};
      gemm_tile(AOs, 136, wob + n0 * 128, 128, m, q, acc);
      float bvv = bo[l * 128 + n0 + m];
      #pragma unroll
      for (int mt = 0; mt < 4; mt++)
        #pragma unroll
        for (int r = 0; r < 4; r++)
          Xs[(mt * 16 + q * 4 + r) * 132 + n0 + m] += acc[mt][r] + bvv;
    }
    __syncthreads();

    // ---- LN2 -> Hs ----
    ln128(Xs, Hs, ln2g + l * 128, ln2b + l * 128, lane, wave);
    __syncthreads();

    // ---- FF: chunk F1 cols by 128; F1 never leaves LDS ----
    {
      f32x4 acc2[4];
      #pragma unroll
      for (int mt = 0; mt < 4; mt++) acc2[mt] = (f32x4){0,0,0,0};
      #pragma unroll 1
      for (int c = 0; c < 4; c++) {
        f32x4 a1[4];
        #pragma unroll
        for (int mt = 0; mt < 4; mt++) a1[mt] = (f32x4){0,0,0,0};
        gemm_tile(Hs, 136, f1wb + (c * 128 + n0) * 128, 128, m, q, a1);
        float b1v = f1b[l * 512 + c * 128 + n0 + m];
        #pragma unroll
        for (int mt = 0; mt < 4; mt++)
          #pragma unroll
          for (int r = 0; r < 4; r++)
            F1s[(mt * 16 + q * 4 + r) * 136 + n0 + m] = f2bf(geluf(a1[mt][r] + b1v));
        __syncthreads();
        gemm_tile(F1s, 136, f2wb + n0 * 512 + c * 128, 512, m, q, acc2);
        __syncthreads();
      }
      float b2v = f2b[l * 128 + n0 + m];
      #pragma unroll
      for (int mt = 0; mt < 4; mt++)
        #pragma unroll
        for (int r = 0; r < 4; r++)
          Xs[(mt * 16 + q * 4 + r) * 132 + n0 + m] += acc2[mt][r] + b2v;
    }
    __syncthreads();
  }

  for (int i = tid; i < 8192; i += 512) Xg[i] = Xs[(i >> 7) * 132 + (i & 127)];
}

// ============================================================
// k_head1: 2-tap conv over streams + bn3 + elu -> G[b][oc][w]. grid (16,4).
// ============================================================
__global__ __launch_bounds__(256) void k_head1(const float* __restrict__ X, const float* __restrict__ ew,
                                               const float* __restrict__ eb, const float* __restrict__ g3,
                                               const float* __restrict__ b3, float* __restrict__ G) {
  __shared__ float Xs[2][8192];   // 64 KB
  int b = blockIdx.x, ot = blockIdx.y;
  int tid = threadIdx.x;
  {
    const float4* x1 = (const float4*)(X + b * 8192);
    const float4* x2 = (const float4*)(X + (16 + b) * 8192);
    float4* s1 = (float4*)&Xs[0][0];
    float4* s2 = (float4*)&Xs[1][0];
    for (int i = tid; i < 2048; i += 256) { s1[i] = x1[i]; s2[i] = x2[i]; }
  }
  __syncthreads();
  int w = tid & 127, og = tid >> 7;
  int oc0 = ot * 16 + og * 8;
  float a[8] = {};
  for (int ic = 0; ic < 64; ic++) {
    float x1v = Xs[0][ic * 128 + w], x2v = Xs[1][ic * 128 + w];
    #pragma unroll
    for (int j = 0; j < 8; j++) {
      a[j] = fmaf(ew[((oc0 + j) * 64 + ic) * 2 + 0], x1v, a[j]);
      a[j] = fmaf(ew[((oc0 + j) * 64 + ic) * 2 + 1], x2v, a[j]);
    }
  }
  #pragma unroll
  for (int j = 0; j < 8; j++) {
    int oc = oc0 + j;
    float v = (a[j] + eb[oc]) * (g3[oc] * BN_S) + b3[oc];
    G[(b * 64 + oc) * 128 + w] = eluf(v);
  }
}

// ============================================================
// k_head2: out[b][c] = G[b] . cw[c] + cb[c]. grid (16,4).
// ============================================================
__global__ __launch_bounds__(256) void k_head2(const float* __restrict__ G, const float* __restrict__ cw,
                                               const float* __restrict__ cb, float* __restrict__ out) {
  __shared__ float red[256];
  int b = blockIdx.x, c = blockIdx.y, tid = threadIdx.x;
  const float4* g4 = (const float4*)(G + b * 8192);
  const float4* c4 = (const float4*)(cw + c * 8192);
  float p = 0.f;
  for (int i = tid; i < 2048; i += 256) {
    float4 g = g4[i], w = c4[i];
    p += g.x * w.x + g.y * w.y + g.z * w.z + g.w * w.w;
  }
  red[tid] = p;
  __syncthreads();
  for (int s = 128; s > 0; s >>= 1) {
    if (tid < s) red[tid] += red[tid + s];
    __syncthreads();
  }
  if (tid == 0) out[b * 4 + c] = red[0] + cb[c];
}

// ============================================================
extern "C" void kernel_launch(void* const* d_in, const int* in_sizes, int n_in,
                              void* d_out, int out_size, void* d_ws, size_t ws_size,
                              hipStream_t stream) {
  const float* x    = (const float*)d_in[0];
  const float* tw1  = (const float*)d_in[1];  const float* tb1 = (const float*)d_in[2];
  const float* tw2  = (const float*)d_in[3];  const float* tb2 = (const float*)d_in[4];
  const float* tw3  = (const float*)d_in[5];  const float* tb3 = (const float*)d_in[6];
  const float* tw4  = (const float*)d_in[7];  const float* tb4 = (const float*)d_in[8];
  const float* bn1g = (const float*)d_in[9];  const float* bn1b = (const float*)d_in[10];
  const float* sw   = (const float*)d_in[11]; const float* sb   = (const float*)d_in[12];
  const float* bn2g = (const float*)d_in[13]; const float* bn2b = (const float*)d_in[14];
  const float* ln1g = (const float*)d_in[15]; const float* ln1b = (const float*)d_in[16];
  const float* ln2g = (const float*)d_in[17]; const float* ln2b = (const float*)d_in[18];
  const float* wq   = (const float*)d_in[19]; const float* bq   = (const float*)d_in[20];
  const float* wk   = (const float*)d_in[21]; const float* bk   = (const float*)d_in[22];
  const float* wv   = (const float*)d_in[23]; const float* bv   = (const float*)d_in[24];
  const float* wo   = (const float*)d_in[25]; const float* bo   = (const float*)d_in[26];
  const float* f1w  = (const float*)d_in[27]; const float* f1b  = (const float*)d_in[28];
  const float* f2w  = (const float*)d_in[29]; const float* f2b  = (const float*)d_in[30];
  const float* ew   = (const float*)d_in[31]; const float* eb   = (const float*)d_in[32];
  const float* g3   = (const float*)d_in[33]; const float* b3   = (const float*)d_in[34];
  const float* cw   = (const float*)d_in[35]; const float* cb   = (const float*)d_in[36];

  float* ws      = (float*)d_ws;
  float* tws1    = ws;               // 8320
  float* c1      = ws + 8320;        // 128
  float* biasEff = ws + 8448;        // 128
  u16*   Wb      = (u16*)(ws + 8576);// 532480 bf16 [u][o][kh] (1.04 MB)
  float* z       = ws + 541056;      // 2048000 [b][o][t]; reused as G after pool
  float* X       = ws + 2589056;     // 262144  [2048][128]
  u16*   Wenc    = (u16*)(ws + 3113344); // 786432 bf16 encoder weights (1.5 MB)
  float* G       = z;                // 131072 (z dead after k_pool)

  k_cvt6<<<768, 256, 0, stream>>>(wq, wk, wv, wo, f1w, f2w, Wenc);
  k_tws1<<<33, 256, 0, stream>>>(tw1, tw2, tw3, tw4, tb1, tb2, tb3, tb4, bn1g, bn1b, tws1, c1);
  k_weff<<<dim3(66, 32), 256, 0, stream>>>(sw, sb, tws1, c1, Wb, biasEff);
  k_conv<<<dim3(16, 2, 16), 256, 0, stream>>>(x, Wb, biasEff, bn2g, bn2b, z);
  k_pool<<<dim3(64, 16), 128, 0, stream>>>(z, X);

  k_enc<<<32, 512, 0, stream>>>(X, Wenc, ln1g, ln1b, ln2g, ln2b, bq, bk, bv, bo, f1b, f2b);

  k_head1<<<dim3(16, 4), 256, 0, stream>>>(X, ew, eb, g3, b3, G);
  k_head2<<<dim3(16, 4), 256, 0, stream>>>(G, cw, cb, (float*)d_out);
}